// Round 12
// baseline (253.072 us; speedup 1.0000x reference)
//
#include <hip/hip_runtime.h>

#define NN 4096
#define CCH 128

// ---------------------------------------------------------------- kernel 0: weight packing + pts4
__global__ __launch_bounds__(256) void transpose_w(
    const float* __restrict__ wq, const float* __restrict__ wk, const float* __restrict__ wv,
    const float* __restrict__ w1, const float* __restrict__ xyz,
    float* __restrict__ wTq, float* __restrict__ wTk, float* __restrict__ wTv,
    float* __restrict__ w1T, float* __restrict__ wPack, float4* __restrict__ pts4) {
  int t = blockIdx.x * 256 + threadIdx.x;
  if (t < 64 * 262) {
    int o = t / 262, c = t - o * 262;
    wTq[c * 64 + o] = wq[t];
    wTk[c * 64 + o] = wk[t];
    wTv[c * 64 + o] = wv[t];
  }
  if (t < 128 * 64) {
    int r = t >> 6, c2 = t & 63;
    w1T[c2 * 128 + r] = w1[t];  // w1T[o][c]
  }
  if (t < 49152) {  // wPack[ct][mh][o][r]
    int r = t & 3, o = (t >> 2) & 63;
    int g = t >> 8;
    int ct = g / 6, mh = g - ct * 6;
    int m = mh >> 1, h = mh & 1;
    const float* wsrc = (m == 0) ? wq : ((m == 1) ? wk : wv);
    wPack[t] = wsrc[o * 262 + (h ? 134 : 6) + 4 * ct + r];
  }
  if (t < 4 * NN) {  // pts4[b*4096+i] = (x,y,z,|x|^2)
    int bb = t >> 12, i = t & 4095;
    const float* xb = xyz + (size_t)bb * 3 * NN;
    float x = xb[i], y = xb[NN + i], z = xb[2 * NN + i];
    pts4[t] = make_float4(x, y, z, x * x + y * y + z * z);
  }
}

// ---------------------------------------------------------------- kernel 1: FUSED proj + knn
// Blocks 0..255: projections (data-independent of kNN) — VMEM-latency-bound.
// Blocks 256..767: kNN halves (round-11 byte-identical math) — VALU-bound.
// Co-resident on each CU (2 x 16-wave blocks), knn's VALU work fills proj's vmcnt stalls.
__global__ __launch_bounds__(1024, 8) void fused_knn_proj(
    const float4* __restrict__ pts4, unsigned long long* __restrict__ keys_ws,
    const float* __restrict__ feature, const float* __restrict__ xyz,
    const float* __restrict__ wTq, const float* __restrict__ wTk, const float* __restrict__ wTv,
    const float* __restrict__ wPack,
    const float* __restrict__ bq, const float* __restrict__ bk, const float* __restrict__ bv,
    float* __restrict__ uqA, float* __restrict__ cq,
    float2* __restrict__ ukv,
    float* __restrict__ ck, float* __restrict__ cv) {
  __shared__ __align__(16) char smem[49664];  // union: knn 49664 B / proj fl 33792 B

  if (blockIdx.x < 256) {
    // ================= proj path: 64 points/block, 16 waves x 4 points =================
    float (*fl)[132] = (float (*)[132])smem;
    const int p0 = blockIdx.x << 6;
    const int b  = p0 >> 12;
    const int n0 = p0 & 4095;
    {
      const int i  = threadIdx.x & 63;
      const int c0 = threadIdx.x >> 6;  // 0..15
      const float* fb = feature + (size_t)b * CCH * NN + n0 + i;
      for (int cc = c0; cc < CCH; cc += 16) fl[i][cc] = fb[(size_t)cc * NN];
      if (threadIdx.x < 192) {
        const int d = threadIdx.x >> 6;
        fl[i][128 + d] = xyz[((size_t)b * 3 + d) * NN + n0 + i];
      }
    }
    __syncthreads();
    const int o  = threadIdx.x & 63;
    const int pg = threadIdx.x >> 6;  // 0..15 -> 4 points each
    const float4* wp = reinterpret_cast<const float4*>(wPack);
    float aU[3][4], aT[3][4];
#pragma unroll
    for (int mm = 0; mm < 3; ++mm)
#pragma unroll
      for (int s = 0; s < 4; ++s) { aU[mm][s] = 0.f; aT[mm][s] = 0.f; }
    for (int ct = 0; ct < 32; ++ct) {
      float4 f4[4];
#pragma unroll
      for (int s = 0; s < 4; ++s)
        f4[s] = *reinterpret_cast<const float4*>(&fl[pg * 4 + s][4 * ct]);
#pragma unroll
      for (int mm = 0; mm < 3; ++mm) {
        const float4 wu = wp[(ct * 6 + 2 * mm) * 64 + o];
        const float4 wt = wp[(ct * 6 + 2 * mm + 1) * 64 + o];
#pragma unroll
        for (int s = 0; s < 4; ++s) {
          aU[mm][s] += wu.x * f4[s].x + wu.y * f4[s].y + wu.z * f4[s].z + wu.w * f4[s].w;
          aT[mm][s] += wt.x * f4[s].x + wt.y * f4[s].y + wt.z * f4[s].z + wt.w * f4[s].w;
        }
      }
    }
    float wxu[3][3], wxt[3][3];
#pragma unroll
    for (int dd = 0; dd < 3; ++dd) {
      wxu[0][dd] = wTq[dd * 64 + o]; wxt[0][dd] = wTq[(3 + dd) * 64 + o];
      wxu[1][dd] = wTk[dd * 64 + o]; wxt[1][dd] = wTk[(3 + dd) * 64 + o];
      wxu[2][dd] = wTv[dd * 64 + o]; wxt[2][dd] = wTv[(3 + dd) * 64 + o];
    }
    const float bo0 = bq[o], bo1 = bk[o], bo2 = bv[o];
#pragma unroll
    for (int s = 0; s < 4; ++s) {
      const int p = pg * 4 + s;
      const float x = fl[p][128], y = fl[p][129], z = fl[p][130];
      const size_t gp = ((size_t)(p0 + p)) * 64 + o;
      float uu, tt;
      uu = aU[0][s] + wxu[0][0] * x + wxu[0][1] * y + wxu[0][2] * z;
      tt = aT[0][s] + wxt[0][0] * x + wxt[0][1] * y + wxt[0][2] * z;
      uqA[gp] = uu; cq[gp] = tt + bo0 - uu;
      const float uk_ = aU[1][s] + wxu[1][0] * x + wxu[1][1] * y + wxu[1][2] * z;
      tt = aT[1][s] + wxt[1][0] * x + wxt[1][1] * y + wxt[1][2] * z;
      ck[gp] = tt + bo1 - uk_;
      const float uv_ = aU[2][s] + wxu[2][0] * x + wxu[2][1] * y + wxu[2][2] * z;
      tt = aT[2][s] + wxt[2][0] * x + wxt[2][1] * y + wxt[2][2] * z;
      cv[gp] = tt + bo2 - uv_;
      ukv[gp] = make_float2(uk_, uv_);
    }
    return;
  }

  // ================= knn path: round-11 byte-identical math =================
  float* bufA = (float*)smem;                                   // 16384 B
  float* bufB = (float*)(smem + 16384);                         // 16384 B
  unsigned long long* hits = (unsigned long long*)(smem + 32768);  // 16640 B
  int* cnt = (int*)(smem + 49408);                              // 256 B
  const int kb = blockIdx.x - 256;
  const int b  = kb >> 7;
  const int g  = (kb >> 1) & 63;
  const int h  = kb & 1;
  const int n0 = g << 6;
  const int ql = threadIdx.x & 63;
  const int ch = __builtin_amdgcn_readfirstlane(threadIdx.x >> 6);
  if (threadIdx.x < 64) cnt[threadIdx.x] = 0;
  const int q = n0 + ql;
  const float4* pb4 = pts4 + ((size_t)b << 12);
  const float4 me = pb4[q];
  float bd0 = 3.0e38f, bd1 = 3.0e38f, bd2 = 3.0e38f, bd3 = 3.0e38f;
  const int m0 = (h << 11) + (ch << 7);
  for (int mb = m0; mb < m0 + 128; mb += 8) {
    float4 P[8];
#pragma unroll
    for (int u = 0; u < 8; ++u) P[u] = pb4[mb + u];
#pragma unroll
    for (int u = 0; u < 8; ++u) {
      float d = me.w + P[u].w - 2.0f * (me.x * P[u].x + me.y * P[u].y + me.z * P[u].z);
      d = (mb + u == q) ? 3.0e38f : d;
      bd3 = __builtin_amdgcn_fmed3f(d, bd2, bd3);
      bd2 = __builtin_amdgcn_fmed3f(d, bd1, bd2);
      bd1 = __builtin_amdgcn_fmed3f(d, bd0, bd1);
      bd0 = fminf(bd0, d);
    }
  }
  {
    const int r0 = (ch * 4) * 64 + ql;
    bufA[r0] = bd0; bufA[r0 + 64] = bd1; bufA[r0 + 128] = bd2; bufA[r0 + 192] = bd3;
  }
  __syncthreads();
  if (ch < 8) {
    const int a0 = (2 * ch) * 4, b0 = (2 * ch + 1) * 4;
    float o8[8]; int pa = 0, pb = 0;
#pragma unroll
    for (int k = 0; k < 8; ++k) {
      float va = (pa < 4) ? bufA[(a0 + pa) * 64 + ql] : 3.0e38f;
      float vb = (pb < 4) ? bufA[(b0 + pb) * 64 + ql] : 3.0e38f;
      bool ta = va <= vb;
      o8[k] = ta ? va : vb;
      pa += ta ? 1 : 0; pb += ta ? 0 : 1;
    }
#pragma unroll
    for (int k = 0; k < 8; ++k) bufB[(ch * 8 + k) * 64 + ql] = o8[k];
  }
  __syncthreads();
  if (ch < 4) {
    const int a0 = (2 * ch) * 8, b0 = (2 * ch + 1) * 8;
    float o16[16]; int pa = 0, pb = 0;
#pragma unroll
    for (int k = 0; k < 16; ++k) {
      float va = (pa < 8) ? bufB[(a0 + pa) * 64 + ql] : 3.0e38f;
      float vb = (pb < 8) ? bufB[(b0 + pb) * 64 + ql] : 3.0e38f;
      bool ta = va <= vb;
      o16[k] = ta ? va : vb;
      pa += ta ? 1 : 0; pb += ta ? 0 : 1;
    }
#pragma unroll
    for (int k = 0; k < 16; ++k) bufA[(ch * 16 + k) * 64 + ql] = o16[k];
  }
  __syncthreads();
  if (ch < 2) {
    const int a0 = (2 * ch) * 16, b0 = (2 * ch + 1) * 16;
    float o16[16]; int pa = 0, pb = 0;
#pragma unroll
    for (int k = 0; k < 16; ++k) {
      float va = bufA[(a0 + pa) * 64 + ql];
      float vb = bufA[(b0 + pb) * 64 + ql];
      bool ta = va <= vb;
      o16[k] = ta ? va : vb;
      pa += ta ? 1 : 0; pb += ta ? 0 : 1;
    }
#pragma unroll
    for (int k = 0; k < 16; ++k) bufB[(ch * 16 + k) * 64 + ql] = o16[k];
  }
  __syncthreads();
  if (ch == 0) {
    float v = 0.f; int pa = 0, pb = 0;
#pragma unroll
    for (int k = 0; k < 16; ++k) {
      float va = bufB[pa * 64 + ql];
      float vb = bufB[(16 + pb) * 64 + ql];
      bool ta = va <= vb;
      v = ta ? va : vb;
      pa += ta ? 1 : 0; pb += ta ? 0 : 1;
    }
    bufA[15 * 64 + ql] = v;
  }
  __syncthreads();
  const float tau = bufA[15 * 64 + ql];
  for (int mb = m0; mb < m0 + 128; mb += 8) {
    float4 P[8];
#pragma unroll
    for (int u = 0; u < 8; ++u) P[u] = pb4[mb + u];
#pragma unroll
    for (int u = 0; u < 8; ++u) {
      float d = me.w + P[u].w - 2.0f * (me.x * P[u].x + me.y * P[u].y + me.z * P[u].z);
      if (d <= tau && (mb + u) != q) {
        int pos = atomicAdd(&cnt[ql], 1);
        if (pos < 32) {
          unsigned int f = __float_as_uint(d);
          f ^= (f >> 31) ? 0xFFFFFFFFu : 0x80000000u;
          hits[pos * 65 + ql] = ((unsigned long long)f << 32) | (unsigned int)(mb + u);
        }
      }
    }
  }
  __syncthreads();
  const int l5 = threadIdx.x & 31;
#pragma unroll
  for (int t = 0; t < 2; ++t) {
    const int qq = (t * 1024 + (int)threadIdx.x) >> 5;
    int nv = cnt[qq]; nv = nv > 32 ? 32 : nv;
    unsigned long long key = (l5 < nv) ? hits[l5 * 65 + qq] : ~0ULL;
#pragma unroll
    for (int k = 2; k <= 32; k <<= 1) {
#pragma unroll
      for (int jm = k >> 1; jm > 0; jm >>= 1) {
        unsigned long long o2 = __shfl_xor(key, jm, 32);
        bool asc = ((l5 & k) == 0);
        bool lower = ((l5 & jm) == 0);
        unsigned long long mn = key < o2 ? key : o2;
        unsigned long long mx = key < o2 ? o2 : key;
        key = (lower == asc) ? mn : mx;
      }
    }
    if (l5 < 16) {
      const size_t gq = (size_t)((b << 12) + n0 + qq);
      keys_ws[((size_t)h << 18) + gq * 16 + l5] = key;
    }
  }
}

// ---------------------------------------------------------------- kernel 1b: merge halves (round-11 exact)
__global__ __launch_bounds__(256) void knn_merge(const unsigned long long* __restrict__ keys_ws,
                                                 int* __restrict__ idxout) {
  const int gq = blockIdx.x * 256 + threadIdx.x;
  const unsigned long long* A  = keys_ws + (size_t)gq * 16;
  const unsigned long long* Bp = keys_ws + (1u << 18) + (size_t)gq * 16;
  int* op = idxout + (size_t)gq * 16;
  int pa = 0, pb = 0;
#pragma unroll
  for (int k = 0; k < 16; ++k) {
    unsigned long long va = A[pa], vb = Bp[pb];
    bool ta = va <= vb;
    op[k] = (int)((ta ? va : vb) & 0xFFFFFFFFu);
    pa += ta ? 1 : 0; pb += ta ? 0 : 1;
  }
}

// ---------------------------------------------------------------- kernel 3: attention core (round-11 exact)
__global__ __launch_bounds__(256) void attn_core(
    const int* __restrict__ idx,
    const float* __restrict__ uqA, const float* __restrict__ cq,
    const float2* __restrict__ ukv,
    const float* __restrict__ ck, const float* __restrict__ cv,
    float* __restrict__ res_ws) {
  __shared__ float kq[4][24][68];
  const int slot = threadIdx.x >> 6;
  const int o    = threadIdx.x & 63;
  const int p = (blockIdx.x << 2) + slot;
  const int b = p >> 12;
  const int myidx = idx[(size_t)p * 16 + (o & 15)];
  const size_t pb = (size_t)p * 64 + o;
  const float cqo = cq[pb], cko = ck[pb], cvo = cv[pb];
  const int rowbase = (b << 12) * 64;
  float v[16];
#pragma unroll
  for (int j = 0; j < 16; ++j) {
    int nb = __shfl(myidx, j);
    int row = rowbase + nb * 64 + o;
    float2 kv = ukv[row];
    kq[slot][j][o] = kv.x + cko;
    v[j] = kv.y + cvo;
    if (j < 8) kq[slot][16 + j][o] = uqA[row] + cqo;
  }
  const int i  = o >> 3;
  const int jj = o & 7;
  const float* qrow = &kq[slot][16 + i][0];
  const float* k0r  = &kq[slot][jj][0];
  const float* k1r  = &kq[slot][8 + jj][0];
  float s0 = 0.f, s1 = 0.f;
#pragma unroll
  for (int t = 0; t < 16; ++t) {
    float4 q4 = *reinterpret_cast<const float4*>(qrow + 4 * t);
    float4 a4 = *reinterpret_cast<const float4*>(k0r + 4 * t);
    float4 c4 = *reinterpret_cast<const float4*>(k1r + 4 * t);
    s0 += q4.x * a4.x + q4.y * a4.y + q4.z * a4.z + q4.w * a4.w;
    s1 += q4.x * c4.x + q4.y * c4.y + q4.z * c4.z + q4.w * c4.w;
  }
  float mx = fmaxf(s0, s1);
  mx = fmaxf(mx, __shfl_xor(mx, 1));
  mx = fmaxf(mx, __shfl_xor(mx, 2));
  mx = fmaxf(mx, __shfl_xor(mx, 4));
  float e0 = __expf(s0 - mx), e1 = __expf(s1 - mx);
  float den = e0 + e1;
  den += __shfl_xor(den, 1);
  den += __shfl_xor(den, 2);
  den += __shfl_xor(den, 4);
  const float inv = 1.0f / den;
  float w0 = e0 * inv, w1s = e1 * inv;
  w0 += __shfl_xor(w0, 8);   w1s += __shfl_xor(w1s, 8);
  w0 += __shfl_xor(w0, 16);  w1s += __shfl_xor(w1s, 16);
  w0 += __shfl_xor(w0, 32);  w1s += __shfl_xor(w1s, 32);
  float res = 0.f;
#pragma unroll
  for (int j = 0; j < 8; ++j) {
    res += __shfl(w0, j)  * v[j];
    res += __shfl(w1s, j) * v[j + 8];
  }
  res_ws[pb] = res;
}

// ---------------------------------------------------------------- kernel 4: output epilogue (round-11 exact)
__global__ __launch_bounds__(512) void out_kernel(
    const float* __restrict__ feature, const float* __restrict__ res,
    const float* __restrict__ w1T, const float* __restrict__ b1,
    float* __restrict__ out) {
  __shared__ float rT[64][66];
  const int p0 = blockIdx.x << 6;
  const int b  = p0 >> 12;
  const int n0 = p0 & 4095;
  {
    const int o = threadIdx.x & 63;
    for (int pp = threadIdx.x >> 6; pp < 64; pp += 8)
      rT[o][pp] = res[(size_t)(p0 + pp) * 64 + o];
  }
  __syncthreads();
  const int n = threadIdx.x & 63;
  const int c0 = (threadIdx.x >> 6) * 16;
  float acc[16];
#pragma unroll
  for (int cc = 0; cc < 16; ++cc) acc[cc] = b1[c0 + cc];
  for (int o = 0; o < 64; ++o) {
    const float rr = rT[o][n];
    const float* wrow = &w1T[o * 128 + c0];
#pragma unroll
    for (int cc = 0; cc < 16; ++cc) acc[cc] += wrow[cc] * rr;
  }
#pragma unroll
  for (int cc = 0; cc < 16; ++cc) {
    const size_t gi = ((size_t)(b * 128 + c0 + cc) << 12) + n0 + n;
    out[gi] = acc[cc] + feature[gi];
  }
}

// ---------------------------------------------------------------- launch
extern "C" void kernel_launch(void* const* d_in, const int* in_sizes, int n_in,
                              void* d_out, int out_size, void* d_ws, size_t ws_size,
                              hipStream_t stream) {
  const float* feature = (const float*)d_in[0];
  const float* xyz     = (const float*)d_in[1];
  const float* wq      = (const float*)d_in[2];
  const float* bq      = (const float*)d_in[3];
  const float* wk      = (const float*)d_in[4];
  const float* bk      = (const float*)d_in[5];
  const float* wv      = (const float*)d_in[6];
  const float* bv      = (const float*)d_in[7];
  const float* w1      = (const float*)d_in[8];
  const float* b1      = (const float*)d_in[9];
  float* out = (float*)d_out;

  char* ws = (char*)d_ws;
  int*    idx  = (int*)ws;                          // 1 MB
  float4* pts4 = (float4*)(ws + (1u << 20));        // 256 KB
  float*  uqA  = (float*)(ws + (2u << 20));         // 4 MB
  float*  cq   = (float*)(ws + (6u << 20));         // 4 MB
  float*  ck   = (float*)(ws + (10u << 20));        // 4 MB
  float*  cv   = (float*)(ws + (14u << 20));        // 4 MB
  float2* ukv  = (float2*)(ws + (18u << 20));       // 8 MB
  float*  res  = (float*)(ws + (26u << 20));        // 4 MB
  float*  wTq  = (float*)(ws + (30u << 20));
  float*  wTk  = wTq + 262 * 64;
  float*  wTv  = wTk + 262 * 64;
  float*  w1T  = wTv + 262 * 64;
  float*  wPk  = w1T + 128 * 64;                    // 49152 floats
  // keys gets its OWN region now — proj (writes uqA) and knn (writes keys) run
  // concurrently inside the fused kernel, so the old aliasing would race.
  unsigned long long* keys = (unsigned long long*)(ws + (31u << 20));  // 4 MB

  transpose_w<<<192, 256, 0, stream>>>(wq, wk, wv, w1, xyz, wTq, wTk, wTv, w1T, wPk, pts4);
  fused_knn_proj<<<768, 1024, 0, stream>>>(pts4, keys, feature, xyz, wTq, wTk, wTv, wPk,
                                           bq, bk, bv, uqA, cq, ukv, ck, cv);
  knn_merge<<<64, 256, 0, stream>>>(keys, idx);
  attn_core<<<4096, 256, 0, stream>>>(idx, uqA, cq, ukv, ck, cv, res);
  out_kernel<<<256, 512, 0, stream>>>(feature, res, w1T, b1, out);
}

// Round 13
// 212.067 us; speedup vs baseline: 1.1934x; 1.1934x over previous
//
#include <hip/hip_runtime.h>

#define NN 4096
#define CCH 128

// ---------------------------------------------------------------- kernel 0: weight packing + pts4
__global__ __launch_bounds__(256) void transpose_w(
    const float* __restrict__ wq, const float* __restrict__ wk, const float* __restrict__ wv,
    const float* __restrict__ w1, const float* __restrict__ xyz,
    float* __restrict__ wTq, float* __restrict__ wTk, float* __restrict__ wTv,
    float* __restrict__ w1T, float* __restrict__ wPack, float4* __restrict__ pts4) {
  int t = blockIdx.x * 256 + threadIdx.x;
  if (t < 64 * 262) {
    int o = t / 262, c = t - o * 262;
    wTq[c * 64 + o] = wq[t];
    wTk[c * 64 + o] = wk[t];
    wTv[c * 64 + o] = wv[t];
  }
  if (t < 128 * 64) {
    int r = t >> 6, c2 = t & 63;
    w1T[c2 * 128 + r] = w1[t];  // w1T[o][c]
  }
  if (t < 49152) {  // wPack[ct][mh][o][r]
    int r = t & 3, o = (t >> 2) & 63;
    int g = t >> 8;
    int ct = g / 6, mh = g - ct * 6;
    int m = mh >> 1, h = mh & 1;
    const float* wsrc = (m == 0) ? wq : ((m == 1) ? wk : wv);
    wPack[t] = wsrc[o * 262 + (h ? 134 : 6) + 4 * ct + r];
  }
  if (t < 4 * NN) {  // pts4[b*4096+i] = (x,y,z,|x|^2)
    int bb = t >> 12, i = t & 4095;
    const float* xb = xyz + (size_t)bb * 3 * NN;
    float x = xb[i], y = xb[NN + i], z = xb[2 * NN + i];
    pts4[t] = make_float4(x, y, z, x * x + y * y + z * z);
  }
}

// ---------------------------------------------------------------- kernel 1: kNN halves (round-11 exact)
__global__ __launch_bounds__(1024, 4) void knn_half(const float4* __restrict__ pts4,
                                                    unsigned long long* __restrict__ keys_ws) {
  __shared__ float bufA[64 * 64];
  __shared__ float bufB[64 * 64];
  __shared__ unsigned long long hits[32 * 65];
  __shared__ int cnt[64];
  const int b  = blockIdx.x >> 7;
  const int g  = (blockIdx.x >> 1) & 63;
  const int h  = blockIdx.x & 1;
  const int n0 = g << 6;
  const int ql = threadIdx.x & 63;
  const int ch = __builtin_amdgcn_readfirstlane(threadIdx.x >> 6);
  if (threadIdx.x < 64) cnt[threadIdx.x] = 0;
  const int q = n0 + ql;
  const float4* pb4 = pts4 + ((size_t)b << 12);
  const float4 me = pb4[q];
  float bd0 = 3.0e38f, bd1 = 3.0e38f, bd2 = 3.0e38f, bd3 = 3.0e38f;
  const int m0 = (h << 11) + (ch << 7);
  for (int mb = m0; mb < m0 + 128; mb += 8) {
    float4 P[8];
#pragma unroll
    for (int u = 0; u < 8; ++u) P[u] = pb4[mb + u];
#pragma unroll
    for (int u = 0; u < 8; ++u) {
      float d = me.w + P[u].w - 2.0f * (me.x * P[u].x + me.y * P[u].y + me.z * P[u].z);
      d = (mb + u == q) ? 3.0e38f : d;
      bd3 = __builtin_amdgcn_fmed3f(d, bd2, bd3);
      bd2 = __builtin_amdgcn_fmed3f(d, bd1, bd2);
      bd1 = __builtin_amdgcn_fmed3f(d, bd0, bd1);
      bd0 = fminf(bd0, d);
    }
  }
  {
    const int r0 = (ch * 4) * 64 + ql;
    bufA[r0] = bd0; bufA[r0 + 64] = bd1; bufA[r0 + 128] = bd2; bufA[r0 + 192] = bd3;
  }
  __syncthreads();
  if (ch < 8) {
    const int a0 = (2 * ch) * 4, b0 = (2 * ch + 1) * 4;
    float o8[8]; int pa = 0, pb = 0;
#pragma unroll
    for (int k = 0; k < 8; ++k) {
      float va = (pa < 4) ? bufA[(a0 + pa) * 64 + ql] : 3.0e38f;
      float vb = (pb < 4) ? bufA[(b0 + pb) * 64 + ql] : 3.0e38f;
      bool ta = va <= vb;
      o8[k] = ta ? va : vb;
      pa += ta ? 1 : 0; pb += ta ? 0 : 1;
    }
#pragma unroll
    for (int k = 0; k < 8; ++k) bufB[(ch * 8 + k) * 64 + ql] = o8[k];
  }
  __syncthreads();
  if (ch < 4) {
    const int a0 = (2 * ch) * 8, b0 = (2 * ch + 1) * 8;
    float o16[16]; int pa = 0, pb = 0;
#pragma unroll
    for (int k = 0; k < 16; ++k) {
      float va = (pa < 8) ? bufB[(a0 + pa) * 64 + ql] : 3.0e38f;
      float vb = (pb < 8) ? bufB[(b0 + pb) * 64 + ql] : 3.0e38f;
      bool ta = va <= vb;
      o16[k] = ta ? va : vb;
      pa += ta ? 1 : 0; pb += ta ? 0 : 1;
    }
#pragma unroll
    for (int k = 0; k < 16; ++k) bufA[(ch * 16 + k) * 64 + ql] = o16[k];
  }
  __syncthreads();
  if (ch < 2) {
    const int a0 = (2 * ch) * 16, b0 = (2 * ch + 1) * 16;
    float o16[16]; int pa = 0, pb = 0;
#pragma unroll
    for (int k = 0; k < 16; ++k) {
      float va = bufA[(a0 + pa) * 64 + ql];
      float vb = bufA[(b0 + pb) * 64 + ql];
      bool ta = va <= vb;
      o16[k] = ta ? va : vb;
      pa += ta ? 1 : 0; pb += ta ? 0 : 1;
    }
#pragma unroll
    for (int k = 0; k < 16; ++k) bufB[(ch * 16 + k) * 64 + ql] = o16[k];
  }
  __syncthreads();
  if (ch == 0) {
    float v = 0.f; int pa = 0, pb = 0;
#pragma unroll
    for (int k = 0; k < 16; ++k) {
      float va = bufB[pa * 64 + ql];
      float vb = bufB[(16 + pb) * 64 + ql];
      bool ta = va <= vb;
      v = ta ? va : vb;
      pa += ta ? 1 : 0; pb += ta ? 0 : 1;
    }
    bufA[15 * 64 + ql] = v;
  }
  __syncthreads();
  const float tau = bufA[15 * 64 + ql];
  for (int mb = m0; mb < m0 + 128; mb += 8) {
    float4 P[8];
#pragma unroll
    for (int u = 0; u < 8; ++u) P[u] = pb4[mb + u];
#pragma unroll
    for (int u = 0; u < 8; ++u) {
      float d = me.w + P[u].w - 2.0f * (me.x * P[u].x + me.y * P[u].y + me.z * P[u].z);
      if (d <= tau && (mb + u) != q) {
        int pos = atomicAdd(&cnt[ql], 1);
        if (pos < 32) {
          unsigned int f = __float_as_uint(d);
          f ^= (f >> 31) ? 0xFFFFFFFFu : 0x80000000u;
          hits[pos * 65 + ql] = ((unsigned long long)f << 32) | (unsigned int)(mb + u);
        }
      }
    }
  }
  __syncthreads();
  const int l5 = threadIdx.x & 31;
#pragma unroll
  for (int t = 0; t < 2; ++t) {
    const int qq = (t * 1024 + (int)threadIdx.x) >> 5;
    int nv = cnt[qq]; nv = nv > 32 ? 32 : nv;
    unsigned long long key = (l5 < nv) ? hits[l5 * 65 + qq] : ~0ULL;
#pragma unroll
    for (int k = 2; k <= 32; k <<= 1) {
#pragma unroll
      for (int jm = k >> 1; jm > 0; jm >>= 1) {
        unsigned long long o2 = __shfl_xor(key, jm, 32);
        bool asc = ((l5 & k) == 0);
        bool lower = ((l5 & jm) == 0);
        unsigned long long mn = key < o2 ? key : o2;
        unsigned long long mx = key < o2 ? o2 : key;
        key = (lower == asc) ? mn : mx;
      }
    }
    if (l5 < 16) {
      const size_t gq = (size_t)((b << 12) + n0 + qq);
      keys_ws[((size_t)h << 18) + gq * 16 + l5] = key;
    }
  }
}

// ---------------------------------------------------------------- kernel 2: projections (round-11 exact)
__global__ __launch_bounds__(512) void proj_kernel(
    const float* __restrict__ feature, const float* __restrict__ xyz,
    const float* __restrict__ wTq, const float* __restrict__ wTk, const float* __restrict__ wTv,
    const float* __restrict__ wPack,
    const float* __restrict__ bq, const float* __restrict__ bk, const float* __restrict__ bv,
    float* __restrict__ uqA, float* __restrict__ cq,
    float2* __restrict__ ukv,
    float* __restrict__ ck, float* __restrict__ cv) {
  __shared__ float fl[64][132];        // 33.8 KB
  __shared__ float4 wl[16 * 6 * 64];   // 96 KB
  const int p0 = blockIdx.x << 6;
  const int b  = p0 >> 12;
  const int n0 = p0 & 4095;
  {
    const int i  = threadIdx.x & 63;
    const int c0 = threadIdx.x >> 6;
    const float* fb = feature + (size_t)b * CCH * NN + n0 + i;
    for (int cc = c0; cc < CCH; cc += 8) fl[i][cc] = fb[(size_t)cc * NN];
    if (threadIdx.x < 192) {
      const int d = threadIdx.x >> 6;
      fl[i][128 + d] = xyz[((size_t)b * 3 + d) * NN + n0 + i];
    }
  }
  const int o  = threadIdx.x & 63;
  const int pg = threadIdx.x >> 6;
  const float4* wp = reinterpret_cast<const float4*>(wPack);
  float aU[3][8], aT[3][8];
#pragma unroll
  for (int mm = 0; mm < 3; ++mm)
#pragma unroll
    for (int s = 0; s < 8; ++s) { aU[mm][s] = 0.f; aT[mm][s] = 0.f; }

  for (int half = 0; half < 2; ++half) {
    __syncthreads();
    for (int d4 = threadIdx.x; d4 < 6144; d4 += 512)
      wl[d4] = wp[half * 6144 + d4];
    __syncthreads();
#pragma unroll 4
    for (int ct = 0; ct < 16; ++ct) {
      float4 w4[6];
#pragma unroll
      for (int mh = 0; mh < 6; ++mh) w4[mh] = wl[(ct * 6 + mh) * 64 + o];
      const int cglob = half * 16 + ct;
#pragma unroll
      for (int s = 0; s < 8; ++s) {
        const float4 f4 = *reinterpret_cast<const float4*>(&fl[pg * 8 + s][4 * cglob]);
#pragma unroll
        for (int mm = 0; mm < 3; ++mm) {
          aU[mm][s] += w4[2 * mm].x * f4.x + w4[2 * mm].y * f4.y + w4[2 * mm].z * f4.z + w4[2 * mm].w * f4.w;
          aT[mm][s] += w4[2 * mm + 1].x * f4.x + w4[2 * mm + 1].y * f4.y + w4[2 * mm + 1].z * f4.z + w4[2 * mm + 1].w * f4.w;
        }
      }
    }
  }
  float wxu[3][3], wxt[3][3];
#pragma unroll
  for (int dd = 0; dd < 3; ++dd) {
    wxu[0][dd] = wTq[dd * 64 + o]; wxt[0][dd] = wTq[(3 + dd) * 64 + o];
    wxu[1][dd] = wTk[dd * 64 + o]; wxt[1][dd] = wTk[(3 + dd) * 64 + o];
    wxu[2][dd] = wTv[dd * 64 + o]; wxt[2][dd] = wTv[(3 + dd) * 64 + o];
  }
  const float bo0 = bq[o], bo1 = bk[o], bo2 = bv[o];
#pragma unroll
  for (int s = 0; s < 8; ++s) {
    const int p = pg * 8 + s;
    const float x = fl[p][128], y = fl[p][129], z = fl[p][130];
    const size_t gp = ((size_t)(p0 + p)) * 64 + o;
    float uu, tt;
    uu = aU[0][s] + wxu[0][0] * x + wxu[0][1] * y + wxu[0][2] * z;
    tt = aT[0][s] + wxt[0][0] * x + wxt[0][1] * y + wxt[0][2] * z;
    uqA[gp] = uu; cq[gp] = tt + bo0 - uu;
    const float uk_ = aU[1][s] + wxu[1][0] * x + wxu[1][1] * y + wxu[1][2] * z;
    tt = aT[1][s] + wxt[1][0] * x + wxt[1][1] * y + wxt[1][2] * z;
    ck[gp] = tt + bo1 - uk_;
    const float uv_ = aU[2][s] + wxu[2][0] * x + wxu[2][1] * y + wxu[2][2] * z;
    tt = aT[2][s] + wxt[2][0] * x + wxt[2][1] * y + wxt[2][2] * z;
    cv[gp] = tt + bo2 - uv_;
    ukv[gp] = make_float2(uk_, uv_);
  }
}

// ---------------------------------------------------------------- kernel 3: attention core + inline half-merge
// Replaces knn_merge: each wave bitonic-merges its point's two sorted half-lists
// (A asc + B reversed = bitonic; 5 shfl_xor stages) -> identical order to 2-ptr merge.
__global__ __launch_bounds__(256) void attn_core(
    const unsigned long long* __restrict__ keys_ws,
    const float* __restrict__ uqA, const float* __restrict__ cq,
    const float2* __restrict__ ukv,
    const float* __restrict__ ck, const float* __restrict__ cv,
    float* __restrict__ res_ws) {
  __shared__ float kq[4][24][68];
  const int slot = threadIdx.x >> 6;
  const int o    = threadIdx.x & 63;
  const int p = (blockIdx.x << 2) + slot;
  const int b = p >> 12;
  // ---- inline merge of the two sorted 16-lists (keys distinct: disjoint idx) ----
  const int l5 = o & 31;
  unsigned long long key =
      (l5 < 16) ? keys_ws[(size_t)p * 16 + l5]
                : keys_ws[((size_t)1 << 18) + (size_t)p * 16 + (31 - l5)];  // B reversed
#pragma unroll
  for (int jm = 16; jm > 0; jm >>= 1) {  // bitonic merge, ascending (k=32 direction)
    unsigned long long o2 = __shfl_xor(key, jm, 32);
    bool lower = ((l5 & jm) == 0);
    unsigned long long mn = key < o2 ? key : o2;
    unsigned long long mx = key < o2 ? o2 : key;
    key = lower ? mn : mx;
  }
  const int kidx = (int)(key & 0xFFFFFFFFu);  // lane j (j<16) holds neighbor j
  const size_t pb = (size_t)p * 64 + o;
  const float cqo = cq[pb], cko = ck[pb], cvo = cv[pb];
  const int rowbase = (b << 12) * 64;
  float v[16];
#pragma unroll
  for (int j = 0; j < 16; ++j) {
    int nb = __shfl(kidx, j);  // width 64: group-0 lane j -> merged entry j
    int row = rowbase + nb * 64 + o;
    float2 kv = ukv[row];
    kq[slot][j][o] = kv.x + cko;
    v[j] = kv.y + cvo;
    if (j < 8) kq[slot][16 + j][o] = uqA[row] + cqo;
  }
  const int i  = o >> 3;
  const int jj = o & 7;
  const float* qrow = &kq[slot][16 + i][0];
  const float* k0r  = &kq[slot][jj][0];
  const float* k1r  = &kq[slot][8 + jj][0];
  float s0 = 0.f, s1 = 0.f;
#pragma unroll
  for (int t = 0; t < 16; ++t) {
    float4 q4 = *reinterpret_cast<const float4*>(qrow + 4 * t);
    float4 a4 = *reinterpret_cast<const float4*>(k0r + 4 * t);
    float4 c4 = *reinterpret_cast<const float4*>(k1r + 4 * t);
    s0 += q4.x * a4.x + q4.y * a4.y + q4.z * a4.z + q4.w * a4.w;
    s1 += q4.x * c4.x + q4.y * c4.y + q4.z * c4.z + q4.w * c4.w;
  }
  float mx = fmaxf(s0, s1);
  mx = fmaxf(mx, __shfl_xor(mx, 1));
  mx = fmaxf(mx, __shfl_xor(mx, 2));
  mx = fmaxf(mx, __shfl_xor(mx, 4));
  float e0 = __expf(s0 - mx), e1 = __expf(s1 - mx);
  float den = e0 + e1;
  den += __shfl_xor(den, 1);
  den += __shfl_xor(den, 2);
  den += __shfl_xor(den, 4);
  const float inv = 1.0f / den;
  float w0 = e0 * inv, w1s = e1 * inv;
  w0 += __shfl_xor(w0, 8);   w1s += __shfl_xor(w1s, 8);
  w0 += __shfl_xor(w0, 16);  w1s += __shfl_xor(w1s, 16);
  w0 += __shfl_xor(w0, 32);  w1s += __shfl_xor(w1s, 32);
  float res = 0.f;
#pragma unroll
  for (int j = 0; j < 8; ++j) {
    res += __shfl(w0, j)  * v[j];
    res += __shfl(w1s, j) * v[j + 8];
  }
  res_ws[pb] = res;
}

// ---------------------------------------------------------------- kernel 4: output epilogue (round-11 exact)
__global__ __launch_bounds__(512) void out_kernel(
    const float* __restrict__ feature, const float* __restrict__ res,
    const float* __restrict__ w1T, const float* __restrict__ b1,
    float* __restrict__ out) {
  __shared__ float rT[64][66];
  const int p0 = blockIdx.x << 6;
  const int b  = p0 >> 12;
  const int n0 = p0 & 4095;
  {
    const int o = threadIdx.x & 63;
    for (int pp = threadIdx.x >> 6; pp < 64; pp += 8)
      rT[o][pp] = res[(size_t)(p0 + pp) * 64 + o];
  }
  __syncthreads();
  const int n = threadIdx.x & 63;
  const int c0 = (threadIdx.x >> 6) * 16;
  float acc[16];
#pragma unroll
  for (int cc = 0; cc < 16; ++cc) acc[cc] = b1[c0 + cc];
  for (int o = 0; o < 64; ++o) {
    const float rr = rT[o][n];
    const float* wrow = &w1T[o * 128 + c0];
#pragma unroll
    for (int cc = 0; cc < 16; ++cc) acc[cc] += wrow[cc] * rr;
  }
#pragma unroll
  for (int cc = 0; cc < 16; ++cc) {
    const size_t gi = ((size_t)(b * 128 + c0 + cc) << 12) + n0 + n;
    out[gi] = acc[cc] + feature[gi];
  }
}

// ---------------------------------------------------------------- launch
extern "C" void kernel_launch(void* const* d_in, const int* in_sizes, int n_in,
                              void* d_out, int out_size, void* d_ws, size_t ws_size,
                              hipStream_t stream) {
  const float* feature = (const float*)d_in[0];
  const float* xyz     = (const float*)d_in[1];
  const float* wq      = (const float*)d_in[2];
  const float* bq      = (const float*)d_in[3];
  const float* wk      = (const float*)d_in[4];
  const float* bk      = (const float*)d_in[5];
  const float* wv      = (const float*)d_in[6];
  const float* bv      = (const float*)d_in[7];
  const float* w1      = (const float*)d_in[8];
  const float* b1      = (const float*)d_in[9];
  float* out = (float*)d_out;

  char* ws = (char*)d_ws;
  float4* pts4 = (float4*)(ws + (1u << 20));        // 256 KB
  float*  uqA  = (float*)(ws + (2u << 20));         // 4 MB
  float*  cq   = (float*)(ws + (6u << 20));         // 4 MB
  float*  ck   = (float*)(ws + (10u << 20));        // 4 MB
  float*  cv   = (float*)(ws + (14u << 20));        // 4 MB
  float2* ukv  = (float2*)(ws + (18u << 20));       // 8 MB
  float*  res  = (float*)(ws + (26u << 20));        // 4 MB
  float*  wTq  = (float*)(ws + (30u << 20));
  float*  wTk  = wTq + 262 * 64;
  float*  wTv  = wTk + 262 * 64;
  float*  w1T  = wTv + 262 * 64;
  float*  wPk  = w1T + 128 * 64;                    // 49152 floats
  // keys has its OWN region: consumed by attn_core, which runs AFTER proj writes uqA.
  unsigned long long* keys = (unsigned long long*)(ws + (31u << 20));  // 4 MB

  transpose_w<<<192, 256, 0, stream>>>(wq, wk, wv, w1, xyz, wTq, wTk, wTv, w1T, wPk, pts4);
  knn_half<<<512, 1024, 0, stream>>>(pts4, keys);
  proj_kernel<<<256, 512, 0, stream>>>(feature, xyz, wTq, wTk, wTv, wPk, bq, bk, bv,
                                       uqA, cq, ukv, ck, cv);
  attn_core<<<4096, 256, 0, stream>>>(keys, uqA, cq, ukv, ck, cv, res);
  out_kernel<<<256, 512, 0, stream>>>(feature, res, w1T, b1, out);
}